// Round 3
// baseline (1140.001 us; speedup 1.0000x reference)
//
#include <hip/hip_runtime.h>
#include <hip/hip_cooperative_groups.h>
#include <cstddef>
#include <cstdint>

namespace cg = cooperative_groups;

#define BATCH_N 32768
#define OUT_DIM 10

typedef unsigned short u16;
typedef __attribute__((ext_vector_type(8))) _Float16 half8;
typedef __attribute__((ext_vector_type(4))) float f32x4;

__device__ __forceinline__ u16 f2h(float v) {
    _Float16 h = (_Float16)v;                 // RTN
    return __builtin_bit_cast(u16, h);
}
__device__ __forceinline__ float h2f(u16 h) {
    return (float)__builtin_bit_cast(_Float16, h);
}
__device__ __forceinline__ float tanh_fast(float x) {
    float e = __expf(2.f * x);        // inf -> 1, 0 -> -1 : robust
    return 1.f - 2.f / (e + 1.f);
}

// ============================================================================
// MEGA-FUSED NETWORK KERNEL (R8 structure, unchanged in R9 — control).
// 128 rows/block, 1024 threads = 16 waves, 1 block/CU, 4 waves/SIMD.
// State [128 x 512] f16 in LDS; A-fragment layout: (m,k) ->
// state[(k>>5)*4096 + (m>>4)*512 + (((k>>3)&3)*16 + (m&15))*8 + (k&7)].
// Weights Wc[layer][c][512] f16, c<256 -> z0 row u=c, c>=256 -> z1 row u=c-256.
// ============================================================================
__global__ __launch_bounds__(1024, 4)
void meganet(const float* __restrict__ X,
             const u16* __restrict__ Wi,        // [256 u][800 k] f16
             const float* __restrict__ b_in,
             const u16* __restrict__ Wc,        // [8][512 c][512 k] f16
             const float* __restrict__ cc,      // [8][512]: [0..255]=c0, [256..511]=c1
             const float* __restrict__ Wo, const float* __restrict__ bo,
             float* __restrict__ out)
{
    __shared__ u16 state[65536];     // 128 KB
    __shared__ float aux[4096];      // 16 KB: x double-buffer, later W_out copy
    const int t = threadIdx.x;
    const int wave = t >> 6, lane = t & 63;
    const int fl = lane & 15, kq = lane >> 4;
    const int b0 = blockIdx.x * 128;

    // ---------------- input stage: v0 = x @ W_in + b_in (K=784, pad 800) ----
    f32x4 ai[8];
#pragma unroll
    for (int a = 0; a < 8; ++a) ai[a] = (f32x4){0.f, 0.f, 0.f, 0.f};

    const u16* bpIn = Wi + (size_t)(wave * 16 + fl) * 800 + kq * 8;

    u16* xbuf = (u16*)aux;           // 2 x 4096 u16 chunk buffers
    const int xr = t >> 3;           // row 0..127
    const int xk = (t & 7) * 4;      // 0..28 step 4
    const size_t xrow = (size_t)(b0 + xr) * 784;
    const int xoff = (xr >> 4) * 512 + ((xk >> 3) * 16 + (xr & 15)) * 8 + (xk & 7);

    half8 IB[2];
    float4 xa;
    {   // prologue: chunk0 -> buf0
        float4 x0 = *(const float4*)(X + xrow + xk);
        ushort4 h;
        h.x = f2h(x0.x); h.y = f2h(x0.y); h.z = f2h(x0.z); h.w = f2h(x0.w);
        *(ushort4*)&xbuf[xoff] = h;
        xa = *(const float4*)(X + xrow + 32 + xk);     // chunk 1
        IB[0] = *(const half8*)(bpIn);                 // chunk 0 weights
    }

#pragma unroll
    for (int ki = 0; ki < 25; ++ki) {
        const int cur = ki & 1, nxt = cur ^ 1;
        __syncthreads();                 // buf[cur] ready; buf[nxt] reads done
        if (ki < 24) {                   // stage chunk ki+1 into buf[nxt]
            ushort4 h;
            h.x = f2h(xa.x); h.y = f2h(xa.y); h.z = f2h(xa.z); h.w = f2h(xa.w);
            *(ushort4*)&xbuf[nxt * 4096 + xoff] = h;
            if (ki < 23) {               // load chunk ki+2 (depth-2)
                const int gk = (ki + 2) * 32 + xk;
                const int ga = (gk <= 780) ? gk : 780;   // Wi packs 0 for k>=784
                xa = *(const float4*)(X + xrow + ga);
            }
            IB[nxt] = *(const half8*)(bpIn + (ki + 1) * 32);
        }
        const u16* rb = xbuf + cur * 4096;
#pragma unroll
        for (int mt = 0; mt < 8; ++mt) {
            half8 af = *(const half8*)&rb[mt * 512 + lane * 8];
            ai[mt] = __builtin_amdgcn_mfma_f32_16x16x32_f16(af, IB[cur], ai[mt], 0, 0, 0);
        }
    }

    // layer-0 ks=0 weight prefetch
    const u16* bp0 = Wc + (size_t)(wave * 16 + fl) * 512 + kq * 8;   // z0 row u
    const u16* bp1 = bp0 + 131072;                                   // z1 row u
    half8 B[2][2];
    B[0][0] = *(const half8*)(bp0);
    B[0][1] = *(const half8*)(bp1);

    // input epilogue: state v0 (k=u), w = 2*tanh(v0) (k=256+u)
    {
        const float bi = b_in[wave * 16 + fl];
        const int u = wave * 16 + fl;
        const int slab = u >> 5;
        const int cbase = ((u >> 3) & 3) * 128 + (u & 7);
#pragma unroll
        for (int mt = 0; mt < 8; ++mt) {
#pragma unroll
            for (int r = 0; r < 4; ++r) {
                float v = ai[mt][r] + bi;
                float w = 2.f * tanh_fast(v);
                const int base = mt * 512 + (kq * 4 + r) * 8 + cbase;
                state[slab * 4096 + base] = f2h(v);
                state[(8 + slab) * 4096 + base] = f2h(w);
            }
        }
    }

    // ---------------- 8 implicit layers ----------------
    for (int L = 0; L < 8; ++L) {
        const float ccv0 = cc[L * 512 + wave * 16 + fl];
        const float ccv1 = cc[L * 512 + 256 + wave * 16 + fl];
        f32x4 acc[8][2];
#pragma unroll
        for (int a = 0; a < 8; ++a) {
            acc[a][0] = (f32x4){0.f, 0.f, 0.f, 0.f};
            acc[a][1] = (f32x4){0.f, 0.f, 0.f, 0.f};
        }
        __syncthreads();   // state ready
#pragma unroll
        for (int ks = 0; ks < 16; ++ks) {
            const int cur = ks & 1, nxt = cur ^ 1;
            if (ks < 15) {             // prefetch next K-step (2 x 16B)
                B[nxt][0] = *(const half8*)(bp0 + (ks + 1) * 32);
                B[nxt][1] = *(const half8*)(bp1 + (ks + 1) * 32);
            } else {                   // prefetch next layer's ks=0 across epilogue
                bp0 += 262144; bp1 += 262144;
                if (L < 7) {
                    B[nxt][0] = *(const half8*)(bp0);
                    B[nxt][1] = *(const half8*)(bp1);
                }
            }
#pragma unroll
            for (int mt = 0; mt < 8; ++mt) {
                half8 af = *(const half8*)&state[ks * 4096 + mt * 512 + lane * 8];
                acc[mt][0] = __builtin_amdgcn_mfma_f32_16x16x32_f16(af, B[cur][0], acc[mt][0], 0, 0, 0);
                acc[mt][1] = __builtin_amdgcn_mfma_f32_16x16x32_f16(af, B[cur][1], acc[mt][1], 0, 0, 0);
            }
        }
        __syncthreads();   // all state reads done; safe to overwrite
        {
            const int u = wave * 16 + fl;
            const int slab = u >> 5;
            const int cbase = ((u >> 3) & 3) * 128 + (u & 7);
#pragma unroll
            for (int mt = 0; mt < 8; ++mt) {
#pragma unroll
                for (int r = 0; r < 4; ++r) {
                    float z0 = acc[mt][0][r] + ccv0;
                    float z1 = acc[mt][1][r] + ccv1;
                    float tv = tanh_fast(z0);
                    const int base = mt * 512 + (kq * 4 + r) * 8 + cbase;
                    state[slab * 4096 + base] = f2h(z0);
                    state[(8 + slab) * 4096 + base] = f2h(z1 + tv);
                }
            }
        }
    }

    // ---------------- output stage: out = v0 @ W_out + b_out ----------------
    __syncthreads();
    for (int i = t; i < 2560; i += 1024) aux[i] = Wo[i];
    __syncthreads();
    {
        const int m = t >> 3;        // 0..127
        const int o = t & 7;
        float s = bo[o];
        for (int kb = 0; kb < 256; kb += 8) {
            const int off = (kb >> 5) * 4096 + (m >> 4) * 512 +
                            (((kb >> 3) & 3) * 16 + (m & 15)) * 8;
            ushort4 h0 = *(const ushort4*)&state[off];
            ushort4 h1 = *(const ushort4*)&state[off + 4];
            s += h2f(h0.x) * aux[(kb + 0) * 10 + o] + h2f(h0.y) * aux[(kb + 1) * 10 + o]
               + h2f(h0.z) * aux[(kb + 2) * 10 + o] + h2f(h0.w) * aux[(kb + 3) * 10 + o]
               + h2f(h1.x) * aux[(kb + 4) * 10 + o] + h2f(h1.y) * aux[(kb + 5) * 10 + o]
               + h2f(h1.z) * aux[(kb + 6) * 10 + o] + h2f(h1.w) * aux[(kb + 7) * 10 + o];
        }
        out[(size_t)(b0 + m) * 10 + o] = s;
    }
    if (t < 256) {
        const int m = t >> 1;
        const int o = 8 + (t & 1);
        float s = bo[o];
        for (int kb = 0; kb < 256; kb += 8) {
            const int off = (kb >> 5) * 4096 + (m >> 4) * 512 +
                            (((kb >> 3) & 3) * 16 + (m & 15)) * 8;
            ushort4 h0 = *(const ushort4*)&state[off];
            ushort4 h1 = *(const ushort4*)&state[off + 4];
            s += h2f(h0.x) * aux[(kb + 0) * 10 + o] + h2f(h0.y) * aux[(kb + 1) * 10 + o]
               + h2f(h0.z) * aux[(kb + 2) * 10 + o] + h2f(h0.w) * aux[(kb + 3) * 10 + o]
               + h2f(h1.x) * aux[(kb + 4) * 10 + o] + h2f(h1.y) * aux[(kb + 5) * 10 + o]
               + h2f(h1.z) * aux[(kb + 6) * 10 + o] + h2f(h1.w) * aux[(kb + 7) * 10 + o];
        }
        out[(size_t)(b0 + m) * 10 + o] = s;
    }
}

// ============================================================================
// R9: ALL prep fused into ONE cooperative kernel (512 blocks x 256 threads,
// 2 blocks/CU co-resident, grid.sync() between stages).  Removes 11 launch
// boundaries, keeps matrices L2-resident, and makes every pack read
// row-contiguous (extra GEMM Q = Bt^T M = P^T replaces the strided -P^T read).
// ============================================================================

// fp32 gemm tile: D[u,v] = EPI( sum_k A[k*256+u] * B[k*256+v] ), 32x32 tile.
// sh must hold >= 2304 floats.  Entry barrier protects prior sh users.
__device__ void gemm_tile(float* D, const float* A, const float* B, const float* E,
                          int epi, int u0, int v0, float* sh)
{
    float (*As)[36] = (float(*)[36])sh;
    float (*Bs)[36] = (float(*)[36])(sh + 1152);
    const int t = threadIdx.x;
    const int tx = t & 15, ty = t >> 4;
    const int lk = t >> 3, lv = (t & 7) << 2;

    float acc[2][2] = {{0.f, 0.f}, {0.f, 0.f}};
    float4 an = *(const float4*)(A + (size_t)lk * 256 + u0 + lv);
    float4 bn = *(const float4*)(B + (size_t)lk * 256 + v0 + lv);

    for (int k0 = 0; k0 < 256; k0 += 32) {
        __syncthreads();                      // k0=0: prior sh users done
        *(float4*)&As[lk][lv] = an;
        *(float4*)&Bs[lk][lv] = bn;
        if (k0 < 224) {
            an = *(const float4*)(A + (size_t)(k0 + 32 + lk) * 256 + u0 + lv);
            bn = *(const float4*)(B + (size_t)(k0 + 32 + lk) * 256 + v0 + lv);
        }
        __syncthreads();
#pragma unroll
        for (int kk = 0; kk < 32; ++kk) {
            float2 a2 = *(const float2*)&As[kk][ty * 2];
            float2 b2 = *(const float2*)&Bs[kk][tx * 2];
            acc[0][0] += a2.x * b2.x; acc[0][1] += a2.x * b2.y;
            acc[1][0] += a2.y * b2.x; acc[1][1] += a2.y * b2.y;
        }
    }

#pragma unroll
    for (int m = 0; m < 2; ++m) {
        const int u = u0 + ty * 2 + m;
        const size_t idx = (size_t)u * 256 + v0 + tx * 2;
        float2 r;
        if (epi == 0) {
            r.x = acc[m][0]; r.y = acc[m][1];
        } else if (epi == 1) {
            r.x = acc[m][0] + ((u == v0 + tx * 2)     ? 2.f : 0.f);
            r.y = acc[m][1] + ((u == v0 + tx * 2 + 1) ? 2.f : 0.f);
        } else {
            float2 e2 = *(const float2*)&E[idx];
            r.x = 2.f * e2.x - acc[m][0];
            r.y = 2.f * e2.y - acc[m][1];
        }
        *(float2*)&D[idx] = r;
    }
}

__global__ __launch_bounds__(256, 2)
void prep_fused(const float* __restrict__ B0, const float* __restrict__ q,
                const float* __restrict__ W_in,
                u16* Wc, u16* Wi, float* cc,
                float* Bt, float* C, float* X, float* X2, float* Y,
                float* P, float* R, float* Q, float* scr, float* coef)
{
    cg::grid_group grid = cg::this_grid();
    __shared__ float sh[2304];       // 9216 B: gemm As/Bs | transpose tile | reductions
    const int b = blockIdx.x;
    const int t = threadIdx.x;
    const int i = b >> 6;            // matrix 0..7
    const int tj = b & 63;           // tile 0..63
    const int u0t = (tj >> 3) * 32, v0t = (tj & 7) * 32;
    const size_t off = (size_t)i * 65536;

    // ---- stage A: C = B0^T B0 + 2I ; Bt transpose ; pack_win ----
    gemm_tile(C + off, B0 + off, B0 + off, nullptr, 1, u0t, v0t, sh);
    __syncthreads();
    {
        float (*tl)[33] = (float(*)[33])sh;
        const int tx = t & 31, ty = t >> 5;
#pragma unroll
        for (int r = 0; r < 32; r += 8)
            tl[ty + r][tx] = B0[off + (size_t)(u0t + ty + r) * 256 + v0t + tx];
        __syncthreads();
#pragma unroll
        for (int r = 0; r < 32; r += 8)
            Bt[off + (size_t)(v0t + ty + r) * 256 + u0t + tx] = tl[tx][ty + r];
    }
    if (b < 200) {                   // W_in transpose-pack: 25 k-tiles x 8 u-tiles
        __syncthreads();
        float (*tl)[33] = (float(*)[33])sh;
        const int tx = t & 31, ty = t >> 5;
        const int k0 = (b % 25) * 32, u0 = (b / 25) * 32;
#pragma unroll
        for (int r = 0; r < 32; r += 8) {
            const int k = k0 + ty + r;
            tl[ty + r][tx] = (k < 784) ? W_in[(size_t)k * 256 + u0 + tx] : 0.f;
        }
        __syncthreads();
#pragma unroll
        for (int r = 0; r < 32; r += 8)
            Wi[(size_t)(u0 + ty + r) * 800 + k0 + tx] = f2h(tl[tx][ty + r]);
    }
    grid.sync();

    // ---- stage B: per-block partial of ||C||_inf (4 columns each) ----
    {
        const int j = t & 3, vr = t >> 2;
        const int c0 = tj * 4;
        float s = 0.f;
#pragma unroll
        for (int vv = 0; vv < 4; ++vv)
            s += fabsf(C[off + (size_t)(vr * 4 + vv) * 256 + c0 + j]);
        sh[t] = s;
        __syncthreads();
        for (int o = 128; o >= 4; o >>= 1) {
            if (t < o) sh[t] += sh[t + o];
            __syncthreads();
        }
        if (t == 0)
            scr[i * 64 + tj] = fmaxf(fmaxf(sh[0], sh[1]), fmaxf(sh[2], sh[3]));
    }
    grid.sync();

    // ---- stage C: reduce 64 partials -> NS seed coefficients ----
    if (b < 8) {
        sh[t] = (t < 64) ? scr[b * 64 + t] : 0.f;
        __syncthreads();
        for (int o = 32; o >= 1; o >>= 1) {
            if (t < o) sh[t] = fmaxf(sh[t], sh[t + o]);
            __syncthreads();
        }
        if (t == 0) {
            const float bt_ = sh[0];               // >= lambda_max; lambda_min >= 2
            const float r = (2.f + bt_) * (2.f + bt_) / (8.f * bt_);
            const float e = (r - 1.f) / (r + 1.f);
            const float bb = -(1.f - e) / (2.f * bt_);
            coef[b * 2] = -bb * (2.f + bt_);
            coef[b * 2 + 1] = bb;
        }
    }
    grid.sync();

    // ---- stage D: seed X = a I + b C ----
    {
        const float a = coef[i * 2], bb = coef[i * 2 + 1];
        const int base = tj * 1024 + t * 4;
#pragma unroll
        for (int n = 0; n < 4; ++n) {
            const int idx = base + n;
            X[off + idx] = bb * C[off + idx] + (((idx >> 8) == (idx & 255)) ? a : 0.f);
        }
    }
    grid.sync();

    // ---- Newton-Schulz x3: X <- 2X - X C X ----
    float* Xc = X; float* Xn = X2;
    for (int it = 0; it < 3; ++it) {
        gemm_tile(Y + off, C + off, Xc + off, nullptr, 0, u0t, v0t, sh);
        grid.sync();
        gemm_tile(Xn + off, Xc + off, Y + off, Xc + off, 2, u0t, v0t, sh);
        grid.sync();
        float* tmp = Xc; Xc = Xn; Xn = tmp;
    }
    // Xc = M = (B^T B + 2I)^{-1} (symmetric)

    // ---- P = M B^T ----
    gemm_tile(P + off, Xc + off, Bt + off, nullptr, 0, u0t, v0t, sh);
    grid.sync();

    // ---- R = B P ; Q = Bt^T M = P^T (for coalesced pack) ----
    gemm_tile(R + off, Bt + off, P + off, nullptr, 0, u0t, v0t, sh);
    gemm_tile(Q + off, Bt + off, Xc + off, nullptr, 0, u0t, v0t, sh);
    grid.sync();

    // ---- pack Wc (all blocks); cc (blocks 0..7) ----
    {
        const int flat0 = b * 4096 + t * 16;     // 16 consecutive k per thread
        const int ip = flat0 >> 18;
        const int c = (flat0 >> 9) & 511;
        const int k0 = flat0 & 511;
        const size_t offp = (size_t)ip * 65536;
        u16* wdst = Wc + (size_t)ip * 262144 + (size_t)c * 512 + k0;
#pragma unroll
        for (int kk = 0; kk < 16; ++kk) {
            const int k = k0 + kk;
            float v;
            if (c < 256) {        // z0 row u=c: [I - R | -P^T]
                v = (k < 256) ? (((c == k) ? 1.f : 0.f) - R[offp + (size_t)c * 256 + k])
                              : (-Q[offp + (size_t)c * 256 + (k - 256)]);
            } else {              // z1 row u=c-256: [P | M]
                const int u = c - 256;
                v = (k < 256) ? P[offp + (size_t)u * 256 + k]
                              : Xc[offp + (size_t)u * 256 + (k - 256)];
            }
            wdst[kk] = f2h(v);
        }
    }
    if (b < 8) {
        float* qs = sh; float* vs = sh + 256; float* c1s = sh + 512;
        const size_t ob = (size_t)b * 65536;
        __syncthreads();
        qs[t] = q[b * 256 + t];
        __syncthreads();
        float s0 = 0.f;
        for (int k = 0; k < 256; ++k) s0 += B0[ob + (size_t)k * 256 + t] * qs[k];
        vs[t] = 0.1f * s0;
        __syncthreads();
        float s = 0.f;
        for (int k = 0; k < 256; ++k) s += Xc[ob + (size_t)k * 256 + t] * vs[k];
        c1s[t] = s;
        cc[b * 512 + 256 + t] = s;
        __syncthreads();
        float s2 = 0.f;
        for (int k = 0; k < 256; ++k) s2 += Bt[ob + (size_t)k * 256 + t] * c1s[k];
        cc[b * 512 + t] = 0.1f * qs[t] - s2;
    }
}

extern "C" void kernel_launch(void* const* d_in, const int* in_sizes, int n_in,
                              void* d_out, int out_size, void* d_ws, size_t ws_size,
                              hipStream_t stream)
{
    const float* x     = (const float*)d_in[0];
    const float* W_in  = (const float*)d_in[1];
    const float* b_in  = (const float*)d_in[2];
    const float* B0    = (const float*)d_in[3];
    const float* q     = (const float*)d_in[4];
    const float* W_out = (const float*)d_in[5];
    const float* b_out = (const float*)d_in[6];

    u16* Wc = (u16*)d_ws;                  // 8 * 262144 u16 = 4 MB
    u16* Wi = Wc + 8 * 262144;             // 256*800 u16
    float* cc = (float*)(Wi + 204800);     // 8*512 floats
    float* F  = cc + 4096;                 // prep scratch: 8 * 524288 floats
    float* Bt = F;
    float* C  = F + 1 * 524288;
    float* X  = F + 2 * 524288;
    float* X2 = F + 3 * 524288;
    float* Y  = F + 4 * 524288;
    float* P  = F + 5 * 524288;
    float* R  = F + 6 * 524288;
    float* Qb = F + 7 * 524288;
    float* scr  = F + 8 * 524288;          // 512 floats
    float* coef = scr + 512;               // 16 floats

    // ---- entire prep in one cooperative kernel ----
    void* args[] = {(void*)&B0, (void*)&q, (void*)&W_in, (void*)&Wc, (void*)&Wi,
                    (void*)&cc, (void*)&Bt, (void*)&C, (void*)&X, (void*)&X2,
                    (void*)&Y, (void*)&P, (void*)&R, (void*)&Qb,
                    (void*)&scr, (void*)&coef};
    hipLaunchCooperativeKernel((void*)prep_fused, dim3(512), dim3(256),
                               args, 0, stream);

    // ---- the whole network in one kernel ----
    meganet<<<BATCH_N / 128, 1024, 0, stream>>>(
        x, Wi, b_in, Wc, cc, W_out, b_out, (float*)d_out);
}

// Round 4
// 657.784 us; speedup vs baseline: 1.7331x; 1.7331x over previous
//
#include <hip/hip_runtime.h>
#include <cstddef>
#include <cstdint>

#define BATCH_N 32768
#define OUT_DIM 10

typedef unsigned short u16;
typedef __attribute__((ext_vector_type(8))) _Float16 half8;
typedef __attribute__((ext_vector_type(4))) float f32x4;

__device__ __forceinline__ u16 f2h(float v) {
    _Float16 h = (_Float16)v;                 // RTN
    return __builtin_bit_cast(u16, h);
}
__device__ __forceinline__ float h2f(u16 h) {
    return (float)__builtin_bit_cast(_Float16, h);
}
__device__ __forceinline__ float tanh_fast(float x) {
    float e = __expf(2.f * x);        // inf -> 1, 0 -> -1 : robust
    return 1.f - 2.f / (e + 1.f);
}

// ============================================================================
// MEGA-FUSED NETWORK KERNEL (R10: row-split waves).
// R8 was LDS-read-bound in the layer loop (per CU-layer: 24.6K cyc ds_read
// vs 5K cyc MFMA).  Now 16 waves = 2 row-halves (g) x 8 col-groups (wc):
// each wave reads HALF the A-panel (rows g*64..g*64+63) and owns 64 output
// cols (u, u+16 of z0 AND z1) -> LDS af-reads halve; acc[4][4]+B[2][4] is
// R7's proven register shape.  Epilogue still has z0/z1 in-thread (no shfl).
// State [128 x 512] f16 in LDS; A-fragment layout: (m,k) ->
// state[(k>>5)*4096 + (m>>4)*512 + (((k>>3)&3)*16 + (m&15))*8 + (k&7)].
// Weights Wc[layer][c][512] f16, c<256 -> z0 row u=c, c>=256 -> z1 row u=c-256.
// ============================================================================
__global__ __launch_bounds__(1024, 4)
void meganet(const float* __restrict__ X,
             const u16* __restrict__ Wi,        // [256 u][800 k] f16
             const float* __restrict__ b_in,
             const u16* __restrict__ Wc,        // [8][512 c][512 k] f16
             const float* __restrict__ cc,      // [8][512]: [0..255]=c0, [256..511]=c1
             const float* __restrict__ Wo, const float* __restrict__ bo,
             float* __restrict__ out)
{
    __shared__ u16 state[65536];     // 128 KB
    __shared__ float aux[4096];      // 16 KB: x double-buffer, later W_out copy
    const int t = threadIdx.x;
    const int wave = t >> 6, lane = t & 63;
    const int fl = lane & 15, kq = lane >> 4;
    const int b0 = blockIdx.x * 128;

    // ---------------- input stage: v0 = x @ W_in + b_in (K=784, pad 800) ----
    // 16 waves x 16 cols; acc 8x1; x staged f16, double-buffered (1 barrier/ki)
    f32x4 ai[8];
#pragma unroll
    for (int a = 0; a < 8; ++a) ai[a] = (f32x4){0.f, 0.f, 0.f, 0.f};

    const u16* bpIn = Wi + (size_t)(wave * 16 + fl) * 800 + kq * 8;

    u16* xbuf = (u16*)aux;           // 2 x 4096 u16 chunk buffers
    const int xr = t >> 3;           // row 0..127
    const int xk = (t & 7) * 4;      // 0..28 step 4
    const size_t xrow = (size_t)(b0 + xr) * 784;
    const int xoff = (xr >> 4) * 512 + ((xk >> 3) * 16 + (xr & 15)) * 8 + (xk & 7);

    half8 IB[2];
    float4 xa;
    {   // prologue: chunk0 -> buf0
        float4 x0 = *(const float4*)(X + xrow + xk);
        ushort4 h;
        h.x = f2h(x0.x); h.y = f2h(x0.y); h.z = f2h(x0.z); h.w = f2h(x0.w);
        *(ushort4*)&xbuf[xoff] = h;
        xa = *(const float4*)(X + xrow + 32 + xk);     // chunk 1
        IB[0] = *(const half8*)(bpIn);                 // chunk 0 weights
    }

#pragma unroll
    for (int ki = 0; ki < 25; ++ki) {
        const int cur = ki & 1, nxt = cur ^ 1;
        __syncthreads();                 // buf[cur] ready; buf[nxt] reads done
        if (ki < 24) {                   // stage chunk ki+1 into buf[nxt]
            ushort4 h;
            h.x = f2h(xa.x); h.y = f2h(xa.y); h.z = f2h(xa.z); h.w = f2h(xa.w);
            *(ushort4*)&xbuf[nxt * 4096 + xoff] = h;
            if (ki < 23) {               // load chunk ki+2 (depth-2)
                const int gk = (ki + 2) * 32 + xk;
                const int ga = (gk <= 780) ? gk : 780;   // Wi packs 0 for k>=784
                xa = *(const float4*)(X + xrow + ga);
            }
            IB[nxt] = *(const half8*)(bpIn + (ki + 1) * 32);
        }
        const u16* rb = xbuf + cur * 4096;
#pragma unroll
        for (int mt = 0; mt < 8; ++mt) {
            half8 af = *(const half8*)&rb[mt * 512 + lane * 8];
            ai[mt] = __builtin_amdgcn_mfma_f32_16x16x32_f16(af, IB[cur], ai[mt], 0, 0, 0);
        }
    }

    // layer mapping: g = row half (0: rows 0..63, 1: 64..127), wc = col group
    const int g = wave >> 3, wc = wave & 7;
    // layer-0 ks=0 weight prefetch (4 cols: z0 u, z0 u+16, z1 u, z1 u+16)
    const u16* p00 = Wc + (size_t)(wc * 32 + fl) * 512 + kq * 8;
    const u16* p01 = p00 + 8192;       // +16 cols
    const u16* p10 = p00 + 131072;     // z1 (+256 cols)
    const u16* p11 = p01 + 131072;
    half8 B[2][4];
    B[0][0] = *(const half8*)p00;
    B[0][1] = *(const half8*)p01;
    B[0][2] = *(const half8*)p10;
    B[0][3] = *(const half8*)p11;

    // input epilogue: state v0 (k=u), w = 2*tanh(v0) (k=256+u)
    {
        const float bi = b_in[wave * 16 + fl];
        const int u = wave * 16 + fl;
        const int slab = u >> 5;
        const int cbase = ((u >> 3) & 3) * 128 + (u & 7);
#pragma unroll
        for (int mt = 0; mt < 8; ++mt) {
#pragma unroll
            for (int r = 0; r < 4; ++r) {
                float v = ai[mt][r] + bi;
                float w = 2.f * tanh_fast(v);
                const int base = mt * 512 + (kq * 4 + r) * 8 + cbase;
                state[slab * 4096 + base] = f2h(v);
                state[(8 + slab) * 4096 + base] = f2h(w);
            }
        }
    }

    // ---------------- 8 implicit layers ----------------
    for (int L = 0; L < 8; ++L) {
        float ccv[4];
        ccv[0] = cc[L * 512 + wc * 32 + fl];
        ccv[1] = cc[L * 512 + wc * 32 + 16 + fl];
        ccv[2] = cc[L * 512 + 256 + wc * 32 + fl];
        ccv[3] = cc[L * 512 + 256 + wc * 32 + 16 + fl];
        f32x4 acc[4][4];
#pragma unroll
        for (int a = 0; a < 4; ++a)
#pragma unroll
            for (int b = 0; b < 4; ++b) acc[a][b] = (f32x4){0.f, 0.f, 0.f, 0.f};
        __syncthreads();   // state ready
#pragma unroll
        for (int ks = 0; ks < 16; ++ks) {
            const int cur = ks & 1, nxt = cur ^ 1;
            if (ks < 15) {             // prefetch next K-step (4 x 16B)
                B[nxt][0] = *(const half8*)(p00 + (ks + 1) * 32);
                B[nxt][1] = *(const half8*)(p01 + (ks + 1) * 32);
                B[nxt][2] = *(const half8*)(p10 + (ks + 1) * 32);
                B[nxt][3] = *(const half8*)(p11 + (ks + 1) * 32);
            } else {                   // prefetch next layer's ks=0 across epilogue
                p00 += 262144; p01 += 262144; p10 += 262144; p11 += 262144;
                if (L < 7) {
                    B[nxt][0] = *(const half8*)p00;
                    B[nxt][1] = *(const half8*)p01;
                    B[nxt][2] = *(const half8*)p10;
                    B[nxt][3] = *(const half8*)p11;
                }
            }
#pragma unroll
            for (int mt = 0; mt < 4; ++mt) {
                half8 af = *(const half8*)&state[ks * 4096 + (g * 4 + mt) * 512 + lane * 8];
                acc[mt][0] = __builtin_amdgcn_mfma_f32_16x16x32_f16(af, B[cur][0], acc[mt][0], 0, 0, 0);
                acc[mt][1] = __builtin_amdgcn_mfma_f32_16x16x32_f16(af, B[cur][1], acc[mt][1], 0, 0, 0);
                acc[mt][2] = __builtin_amdgcn_mfma_f32_16x16x32_f16(af, B[cur][2], acc[mt][2], 0, 0, 0);
                acc[mt][3] = __builtin_amdgcn_mfma_f32_16x16x32_f16(af, B[cur][3], acc[mt][3], 0, 0, 0);
            }
        }
        __syncthreads();   // all state reads done; safe to overwrite
        // epilogue: thread owns z0[u],z1[u] and z0[u+16],z1[u+16] on its row half
#pragma unroll
        for (int nt2 = 0; nt2 < 2; ++nt2) {
            const int u = wc * 32 + nt2 * 16 + fl;
            const int slab = u >> 5;
            const int cbase = ((u >> 3) & 3) * 128 + (u & 7);
#pragma unroll
            for (int mt = 0; mt < 4; ++mt) {
                const int rb = (g * 4 + mt) * 512;
#pragma unroll
                for (int r = 0; r < 4; ++r) {
                    float z0 = acc[mt][nt2][r] + ccv[nt2];
                    float z1 = acc[mt][2 + nt2][r] + ccv[2 + nt2];
                    float tv = tanh_fast(z0);
                    const int base = rb + (kq * 4 + r) * 8 + cbase;
                    state[slab * 4096 + base] = f2h(z0);
                    state[(8 + slab) * 4096 + base] = f2h(z1 + tv);
                }
            }
        }
    }

    // ---------------- output stage: out = v0 @ W_out + b_out ----------------
    __syncthreads();
    for (int i = t; i < 2560; i += 1024) aux[i] = Wo[i];
    __syncthreads();
    {
        const int m = t >> 3;        // 0..127
        const int o = t & 7;
        float s = bo[o];
        for (int kb = 0; kb < 256; kb += 8) {
            const int off = (kb >> 5) * 4096 + (m >> 4) * 512 +
                            (((kb >> 3) & 3) * 16 + (m & 15)) * 8;
            ushort4 h0 = *(const ushort4*)&state[off];
            ushort4 h1 = *(const ushort4*)&state[off + 4];
            s += h2f(h0.x) * aux[(kb + 0) * 10 + o] + h2f(h0.y) * aux[(kb + 1) * 10 + o]
               + h2f(h0.z) * aux[(kb + 2) * 10 + o] + h2f(h0.w) * aux[(kb + 3) * 10 + o]
               + h2f(h1.x) * aux[(kb + 4) * 10 + o] + h2f(h1.y) * aux[(kb + 5) * 10 + o]
               + h2f(h1.z) * aux[(kb + 6) * 10 + o] + h2f(h1.w) * aux[(kb + 7) * 10 + o];
        }
        out[(size_t)(b0 + m) * 10 + o] = s;
    }
    if (t < 256) {
        const int m = t >> 1;
        const int o = 8 + (t & 1);
        float s = bo[o];
        for (int kb = 0; kb < 256; kb += 8) {
            const int off = (kb >> 5) * 4096 + (m >> 4) * 512 +
                            (((kb >> 3) & 3) * 16 + (m & 15)) * 8;
            ushort4 h0 = *(const ushort4*)&state[off];
            ushort4 h1 = *(const ushort4*)&state[off + 4];
            s += h2f(h0.x) * aux[(kb + 0) * 10 + o] + h2f(h0.y) * aux[(kb + 1) * 10 + o]
               + h2f(h0.z) * aux[(kb + 2) * 10 + o] + h2f(h0.w) * aux[(kb + 3) * 10 + o]
               + h2f(h1.x) * aux[(kb + 4) * 10 + o] + h2f(h1.y) * aux[(kb + 5) * 10 + o]
               + h2f(h1.z) * aux[(kb + 6) * 10 + o] + h2f(h1.w) * aux[(kb + 7) * 10 + o];
        }
        out[(size_t)(b0 + m) * 10 + o] = s;
    }
}

// ============================================================================
// R10 prep: multi-launch again (grid.sync measured ~70us/sync in R9 — dead).
// GEMMs: 64x64 tile / 4x4 acc / float4 LDS reads (0.125 LDS instr/FMA, 4x
// better than the 32x32 version that was LDS-issue-bound at ~20us/GEMM).
// ============================================================================

// D[u,v] = EPI( sum_k A[k*256+u] * B[k*256+v] ), one 64x64 tile per block.
__device__ __forceinline__ void gemm64_body(float* __restrict__ D,
        const float* __restrict__ A, const float* __restrict__ Bm,
        const float* __restrict__ E, int epi, size_t off, int u0, int v0)
{
    __shared__ float As[16][64];
    __shared__ float Bs[16][64];
    const float* Ai = A + off;
    const float* Bi = Bm + off;
    const int t  = threadIdx.x;
    const int tx = t & 15, ty = t >> 4;
    const int lk = t >> 4, lv = (t & 15) << 2;

    float acc[4][4];
#pragma unroll
    for (int m = 0; m < 4; ++m)
#pragma unroll
        for (int n = 0; n < 4; ++n) acc[m][n] = 0.f;

    float4 an = *(const float4*)(Ai + (size_t)lk * 256 + u0 + lv);
    float4 bn = *(const float4*)(Bi + (size_t)lk * 256 + v0 + lv);

    for (int k0 = 0; k0 < 256; k0 += 16) {
        if (k0) __syncthreads();
        *(float4*)&As[lk][lv] = an;
        *(float4*)&Bs[lk][lv] = bn;
        if (k0 < 240) {
            an = *(const float4*)(Ai + (size_t)(k0 + 16 + lk) * 256 + u0 + lv);
            bn = *(const float4*)(Bi + (size_t)(k0 + 16 + lk) * 256 + v0 + lv);
        }
        __syncthreads();
#pragma unroll
        for (int kk = 0; kk < 16; ++kk) {
            float af[4], bf[4];
            *(float4*)&af[0] = *(const float4*)&As[kk][ty * 4];
            *(float4*)&bf[0] = *(const float4*)&Bs[kk][tx * 4];
#pragma unroll
            for (int m = 0; m < 4; ++m)
#pragma unroll
                for (int n = 0; n < 4; ++n) acc[m][n] += af[m] * bf[n];
        }
    }

#pragma unroll
    for (int m = 0; m < 4; ++m) {
        const int u = u0 + ty * 4 + m;
        const size_t idx = off + (size_t)u * 256 + v0 + tx * 4;
        float4 r; float* rf = &r.x;
        if (epi == 0) {
#pragma unroll
            for (int n = 0; n < 4; ++n) rf[n] = acc[m][n];
        } else if (epi == 1) {
#pragma unroll
            for (int n = 0; n < 4; ++n)
                rf[n] = acc[m][n] + ((u == v0 + tx * 4 + n) ? 2.f : 0.f);
        } else {
            float4 e = *(const float4*)&E[idx];
            const float* ef = &e.x;
#pragma unroll
            for (int n = 0; n < 4; ++n) rf[n] = 2.f * ef[n] - acc[m][n];
        }
        *(float4*)&D[idx] = r;
    }
}

template<int EPI>
__launch_bounds__(256)
__global__ void gemm64(float* __restrict__ D, const float* __restrict__ A,
                       const float* __restrict__ Bm, const float* __restrict__ E)
{
    gemm64_body(D, A, Bm, E, EPI, (size_t)blockIdx.z * 65536,
                blockIdx.y * 64, blockIdx.x * 64);
}

// R = B P and Q = B M (= P^T) in ONE dispatch (z 0..15) — full-chip.
__launch_bounds__(256)
__global__ void gemmRQ(float* __restrict__ Rm, float* __restrict__ Qm,
                       const float* __restrict__ Bt, const float* __restrict__ P,
                       const float* __restrict__ M)
{
    const int z = blockIdx.z;
    float* D = (z < 8) ? Rm : Qm;
    const float* Bs = (z < 8) ? P : M;
    gemm64_body(D, Bt, Bs, nullptr, 0, (size_t)(z & 7) * 65536,
                blockIdx.y * 64, blockIdx.x * 64);
}

// fused: Bt transpose (blocks 0..63) + W_in transpose-pack (blocks 64..263)
__launch_bounds__(256)
__global__ void prep_a(const float* __restrict__ B0, const float* __restrict__ W_in,
                       float* __restrict__ Bt, u16* __restrict__ Wi)
{
    __shared__ float tl[32][33];
    const int b = blockIdx.x, t = threadIdx.x;
    const int tx = t & 31, ty = t >> 5;   // 32 x 8
    if (b < 64) {
        const int i = b >> 3;
        const size_t off = (size_t)i * 65536;
        const int u0 = (b & 7) * 32;
        for (int k0 = 0; k0 < 256; k0 += 32) {
            __syncthreads();
#pragma unroll
            for (int r = 0; r < 32; r += 8)
                tl[ty + r][tx] = B0[off + (size_t)(u0 + ty + r) * 256 + k0 + tx];
            __syncthreads();
#pragma unroll
            for (int r = 0; r < 32; r += 8)
                Bt[off + (size_t)(k0 + ty + r) * 256 + u0 + tx] = tl[tx][ty + r];
        }
    } else {
        const int bb = b - 64;            // 0..199: 25 k-tiles x 8 u-tiles
        const int k0 = (bb % 25) * 32, u0 = (bb / 25) * 32;
#pragma unroll
        for (int r = 0; r < 32; r += 8) {
            const int k = k0 + ty + r;
            tl[ty + r][tx] = (k < 784) ? W_in[(size_t)k * 256 + u0 + tx] : 0.f;
        }
        __syncthreads();
#pragma unroll
        for (int r = 0; r < 32; r += 8)
            Wi[(size_t)(u0 + ty + r) * 800 + k0 + tx] = f2h(tl[tx][ty + r]);
    }
}

// row sums of |C| (C symmetric -> ||C||_inf): 512 blocks x 4 rows
__launch_bounds__(256)
__global__ void prep_rowsum(const float* __restrict__ C, float* __restrict__ scr)
{
    __shared__ float red[256];
    const int b = blockIdx.x, t = threadIdx.x;
    const int i = b >> 6, r0 = (b & 63) * 4;
    const int rr = t >> 6, j = t & 63;        // 4 rows x 64 threads
    float4 c4 = *(const float4*)&C[(size_t)i * 65536 + (size_t)(r0 + rr) * 256 + j * 4];
    red[t] = fabsf(c4.x) + fabsf(c4.y) + fabsf(c4.z) + fabsf(c4.w);
    __syncthreads();
    for (int o = 32; o >= 1; o >>= 1) {
        if (j < o) red[t] += red[t + o];
        __syncthreads();
    }
    if (t < 4) scr[i * 256 + r0 + t] = red[t * 64];
}

// reduce row sums -> NS seed X = a I + b C (each block: 1/64 of a matrix)
__launch_bounds__(256)
__global__ void prep_seed(const float* __restrict__ C, const float* __restrict__ scr,
                          float* __restrict__ X)
{
    __shared__ float red[256];
    const int b = blockIdx.x, t = threadIdx.x;
    const int i = b >> 6, tj = b & 63;
    red[t] = scr[i * 256 + t];
    __syncthreads();
    for (int o = 128; o >= 1; o >>= 1) {
        if (t < o) red[t] = fmaxf(red[t], red[t + o]);
        __syncthreads();
    }
    const float bt_ = red[0];                  // >= lambda_max; lambda_min >= 2
    const float r = (2.f + bt_) * (2.f + bt_) / (8.f * bt_);
    const float e = (r - 1.f) / (r + 1.f);
    const float bb = -(1.f - e) / (2.f * bt_);
    const float a = -bb * (2.f + bt_);
    const size_t off = (size_t)i * 65536;
    const int base = tj * 1024 + t * 4;
    float4 c4 = *(const float4*)&C[off + base];
    const float* cf = &c4.x;
    float4 x4; float* xf = &x4.x;
#pragma unroll
    for (int n = 0; n < 4; ++n) {
        const int idx = base + n;
        xf[n] = bb * cf[n] + (((idx >> 8) == (idx & 255)) ? a : 0.f);
    }
    *(float4*)&X[off + base] = x4;
}

// bq = 0.1*B0^T q, c1 = M bq (cc slots 256..511), c0 = 0.1 q - B c1 (0..255)
__launch_bounds__(256)
__global__ void prep_cc2(const float* __restrict__ M, const float* __restrict__ Bt,
                         const float* __restrict__ B0, const float* __restrict__ q,
                         float* __restrict__ cc)
{
    __shared__ float qs[256];
    __shared__ float vs[256];
    __shared__ float c1s[256];
    const int i = blockIdx.x;
    const int u = threadIdx.x;
    qs[u] = q[i * 256 + u];
    __syncthreads();
    float s0 = 0.f;
    for (int k = 0; k < 256; ++k) s0 += B0[(size_t)i * 65536 + (size_t)k * 256 + u] * qs[k];
    vs[u] = 0.1f * s0;
    __syncthreads();
    float s = 0.f;
    for (int k = 0; k < 256; ++k) s += M[(size_t)i * 65536 + (size_t)k * 256 + u] * vs[k];
    c1s[u] = s;
    cc[i * 512 + 256 + u] = s;
    __syncthreads();
    float s2 = 0.f;
    for (int k = 0; k < 256; ++k) s2 += Bt[(size_t)i * 65536 + (size_t)k * 256 + u] * c1s[k];
    cc[i * 512 + u] = 0.1f * qs[u] - s2;
}

// Wc[i][c][512] f16 pack, all reads row-contiguous (Q = P^T precomputed)
__launch_bounds__(256)
__global__ void pack_wcomb(const float* __restrict__ P, const float* __restrict__ R,
                           const float* __restrict__ Q, const float* __restrict__ M,
                           u16* __restrict__ W)
{
    const int i = blockIdx.y;
    const int e = blockIdx.x * 256 + threadIdx.x;   // 0..262143
    const int c = e >> 9, k = e & 511;
    const size_t off = (size_t)i * 65536;
    float v;
    if (c < 256) {        // z0 row u=c: [I - R | -P^T]
        if (k < 256) v = ((c == k) ? 1.f : 0.f) - R[off + (size_t)c * 256 + k];
        else         v = -Q[off + (size_t)c * 256 + (k - 256)];
    } else {              // z1 row u=c-256: [P | M]
        const int u = c - 256;
        if (k < 256) v = P[off + (size_t)u * 256 + k];
        else         v = M[off + (size_t)u * 256 + (k - 256)];
    }
    W[(size_t)i * 262144 + (size_t)c * 512 + k] = f2h(v);
}

extern "C" void kernel_launch(void* const* d_in, const int* in_sizes, int n_in,
                              void* d_out, int out_size, void* d_ws, size_t ws_size,
                              hipStream_t stream)
{
    const float* x     = (const float*)d_in[0];
    const float* W_in  = (const float*)d_in[1];
    const float* b_in  = (const float*)d_in[2];
    const float* B0    = (const float*)d_in[3];
    const float* q     = (const float*)d_in[4];
    const float* W_out = (const float*)d_in[5];
    const float* b_out = (const float*)d_in[6];

    u16* Wc = (u16*)d_ws;                  // 8 * 262144 u16 = 4 MB
    u16* Wi = Wc + 8 * 262144;             // 256*800 u16
    float* cc = (float*)(Wi + 204800);     // 8*512 floats
    float* F  = cc + 4096;                 // prep scratch: 8 * 524288 floats
    float* Bt = F;
    float* C  = F + 1 * 524288;
    float* X  = F + 2 * 524288;
    float* X2 = F + 3 * 524288;
    float* Y  = F + 4 * 524288;
    float* P  = F + 5 * 524288;
    float* R  = F + 6 * 524288;
    float* Qb = F + 7 * 524288;
    float* scr = F + 8 * 524288;           // 2048 floats

    // ---- per-layer matrix prep (fp32, multi-launch) ----
    prep_a<<<264, 256, 0, stream>>>(B0, W_in, Bt, Wi);
    gemm64<1><<<dim3(4, 4, 8), 256, 0, stream>>>(C, B0, B0, nullptr); // C = B^T B + 2I
    prep_rowsum<<<512, 256, 0, stream>>>(C, scr);
    prep_seed<<<512, 256, 0, stream>>>(C, scr, X);
    float* Xc = X; float* Xn = X2;
    for (int it = 0; it < 3; ++it) {   // Newton-Schulz: X <- 2X - X C X
        gemm64<0><<<dim3(4, 4, 8), 256, 0, stream>>>(Y, C, Xc, nullptr);
        gemm64<2><<<dim3(4, 4, 8), 256, 0, stream>>>(Xn, Xc, Y, Xc);
        float* tmp = Xc; Xc = Xn; Xn = tmp;
    }
    // Xc = M = (B^T B + 2I)^{-1} (symmetric)
    gemm64<0><<<dim3(4, 4, 8), 256, 0, stream>>>(P, Xc, Bt, nullptr);   // P = M B^T
    gemmRQ<<<dim3(4, 4, 16), 256, 0, stream>>>(R, Qb, Bt, P, Xc);       // R = B P ; Q = P^T
    prep_cc2<<<8, 256, 0, stream>>>(Xc, Bt, B0, q, cc);

    // ---- weight pack ----
    pack_wcomb<<<dim3(1024, 8), 256, 0, stream>>>(P, R, Qb, Xc, Wc);

    // ---- the whole network in one kernel ----
    meganet<<<BATCH_N / 128, 1024, 0, stream>>>(
        x, Wi, b_in, Wc, cc, W_out, b_out, (float*)d_out);
}

// Round 5
// 461.397 us; speedup vs baseline: 2.4708x; 1.4256x over previous
//
#include <hip/hip_runtime.h>
#include <cstddef>
#include <cstdint>

#define BATCH_N 32768
#define OUT_DIM 10
#define HS 524288   // split-half offset in floats (8 matrices x 65536)

typedef unsigned short u16;
typedef __attribute__((ext_vector_type(8))) _Float16 half8;
typedef __attribute__((ext_vector_type(4))) float f32x4;

__device__ __forceinline__ u16 f2h(float v) {
    _Float16 h = (_Float16)v;                 // RTN
    return __builtin_bit_cast(u16, h);
}
__device__ __forceinline__ float h2f(u16 h) {
    return (float)__builtin_bit_cast(_Float16, h);
}
__device__ __forceinline__ float tanh_fast(float x) {
    float e = __expf(2.f * x);        // inf -> 1, 0 -> -1 : robust
    return 1.f - 2.f / (e + 1.f);
}

// ============================================================================
// MEGA-FUSED NETWORK KERNEL — R8 structure verbatim (proven 245.8us).
// R10's row-split variant spilled to scratch (WRITE_SIZE 138MB) — reverted.
// 128 rows/block, 1024 threads = 16 waves, 1 block/CU, 4 waves/SIMD.
// State [128 x 512] f16 in LDS; A-fragment layout: (m,k) ->
// state[(k>>5)*4096 + (m>>4)*512 + (((k>>3)&3)*16 + (m&15))*8 + (k&7)].
// Weights Wc[layer][c][512] f16, c<256 -> z0 row u=c, c>=256 -> z1 row u=c-256.
// ============================================================================
__global__ __launch_bounds__(1024, 4)
void meganet(const float* __restrict__ X,
             const u16* __restrict__ Wi,        // [256 u][800 k] f16
             const float* __restrict__ b_in,
             const u16* __restrict__ Wc,        // [8][512 c][512 k] f16
             const float* __restrict__ cc,      // [8][512]: [0..255]=c0, [256..511]=c1
             const float* __restrict__ Wo, const float* __restrict__ bo,
             float* __restrict__ out)
{
    __shared__ u16 state[65536];     // 128 KB
    __shared__ float aux[4096];      // 16 KB: x double-buffer, later W_out copy
    const int t = threadIdx.x;
    const int wave = t >> 6, lane = t & 63;
    const int fl = lane & 15, kq = lane >> 4;
    const int b0 = blockIdx.x * 128;

    // ---------------- input stage: v0 = x @ W_in + b_in (K=784, pad 800) ----
    f32x4 ai[8];
#pragma unroll
    for (int a = 0; a < 8; ++a) ai[a] = (f32x4){0.f, 0.f, 0.f, 0.f};

    const u16* bpIn = Wi + (size_t)(wave * 16 + fl) * 800 + kq * 8;

    u16* xbuf = (u16*)aux;           // 2 x 4096 u16 chunk buffers
    const int xr = t >> 3;           // row 0..127
    const int xk = (t & 7) * 4;      // 0..28 step 4
    const size_t xrow = (size_t)(b0 + xr) * 784;
    const int xoff = (xr >> 4) * 512 + ((xk >> 3) * 16 + (xr & 15)) * 8 + (xk & 7);

    half8 IB[2];
    float4 xa;
    {   // prologue: chunk0 -> buf0
        float4 x0 = *(const float4*)(X + xrow + xk);
        ushort4 h;
        h.x = f2h(x0.x); h.y = f2h(x0.y); h.z = f2h(x0.z); h.w = f2h(x0.w);
        *(ushort4*)&xbuf[xoff] = h;
        xa = *(const float4*)(X + xrow + 32 + xk);     // chunk 1
        IB[0] = *(const half8*)(bpIn);                 // chunk 0 weights
    }

#pragma unroll
    for (int ki = 0; ki < 25; ++ki) {
        const int cur = ki & 1, nxt = cur ^ 1;
        __syncthreads();                 // buf[cur] ready; buf[nxt] reads done
        if (ki < 24) {                   // stage chunk ki+1 into buf[nxt]
            ushort4 h;
            h.x = f2h(xa.x); h.y = f2h(xa.y); h.z = f2h(xa.z); h.w = f2h(xa.w);
            *(ushort4*)&xbuf[nxt * 4096 + xoff] = h;
            if (ki < 23) {               // load chunk ki+2 (depth-2)
                const int gk = (ki + 2) * 32 + xk;
                const int ga = (gk <= 780) ? gk : 780;   // Wi packs 0 for k>=784
                xa = *(const float4*)(X + xrow + ga);
            }
            IB[nxt] = *(const half8*)(bpIn + (ki + 1) * 32);
        }
        const u16* rb = xbuf + cur * 4096;
#pragma unroll
        for (int mt = 0; mt < 8; ++mt) {
            half8 af = *(const half8*)&rb[mt * 512 + lane * 8];
            ai[mt] = __builtin_amdgcn_mfma_f32_16x16x32_f16(af, IB[cur], ai[mt], 0, 0, 0);
        }
    }

    // layer-0 ks=0 weight prefetch: global, independent of LDS -> issue early
    const u16* bp0 = Wc + (size_t)(wave * 16 + fl) * 512 + kq * 8;   // z0 row u
    const u16* bp1 = bp0 + 131072;                                   // z1 row u
    half8 B[2][2];
    B[0][0] = *(const half8*)(bp0);
    B[0][1] = *(const half8*)(bp1);

    // input epilogue: state v0 (k=u), w = 2*tanh(v0) (k=256+u)
    {
        const float bi = b_in[wave * 16 + fl];
        const int u = wave * 16 + fl;
        const int slab = u >> 5;
        const int cbase = ((u >> 3) & 3) * 128 + (u & 7);
#pragma unroll
        for (int mt = 0; mt < 8; ++mt) {
#pragma unroll
            for (int r = 0; r < 4; ++r) {
                float v = ai[mt][r] + bi;
                float w = 2.f * tanh_fast(v);
                const int base = mt * 512 + (kq * 4 + r) * 8 + cbase;
                state[slab * 4096 + base] = f2h(v);
                state[(8 + slab) * 4096 + base] = f2h(w);
            }
        }
    }

    // ---------------- 8 implicit layers ----------------
    for (int L = 0; L < 8; ++L) {
        const float ccv0 = cc[L * 512 + wave * 16 + fl];
        const float ccv1 = cc[L * 512 + 256 + wave * 16 + fl];
        f32x4 acc[8][2];
#pragma unroll
        for (int a = 0; a < 8; ++a) {
            acc[a][0] = (f32x4){0.f, 0.f, 0.f, 0.f};
            acc[a][1] = (f32x4){0.f, 0.f, 0.f, 0.f};
        }
        __syncthreads();   // state ready
#pragma unroll
        for (int ks = 0; ks < 16; ++ks) {
            const int cur = ks & 1, nxt = cur ^ 1;
            if (ks < 15) {             // prefetch next K-step (2 x 16B)
                B[nxt][0] = *(const half8*)(bp0 + (ks + 1) * 32);
                B[nxt][1] = *(const half8*)(bp1 + (ks + 1) * 32);
            } else {                   // prefetch next layer's ks=0 across epilogue
                bp0 += 262144; bp1 += 262144;
                if (L < 7) {
                    B[nxt][0] = *(const half8*)(bp0);
                    B[nxt][1] = *(const half8*)(bp1);
                }
            }
#pragma unroll
            for (int mt = 0; mt < 8; ++mt) {
                half8 af = *(const half8*)&state[ks * 4096 + mt * 512 + lane * 8];
                acc[mt][0] = __builtin_amdgcn_mfma_f32_16x16x32_f16(af, B[cur][0], acc[mt][0], 0, 0, 0);
                acc[mt][1] = __builtin_amdgcn_mfma_f32_16x16x32_f16(af, B[cur][1], acc[mt][1], 0, 0, 0);
            }
        }
        __syncthreads();   // all state reads done; safe to overwrite
        // epilogue: thread owns z0[u] and z1[u] -> tanh once, no shfl
        {
            const int u = wave * 16 + fl;
            const int slab = u >> 5;
            const int cbase = ((u >> 3) & 3) * 128 + (u & 7);
#pragma unroll
            for (int mt = 0; mt < 8; ++mt) {
#pragma unroll
                for (int r = 0; r < 4; ++r) {
                    float z0 = acc[mt][0][r] + ccv0;
                    float z1 = acc[mt][1][r] + ccv1;
                    float tv = tanh_fast(z0);
                    const int base = mt * 512 + (kq * 4 + r) * 8 + cbase;
                    state[slab * 4096 + base] = f2h(z0);
                    state[(8 + slab) * 4096 + base] = f2h(z1 + tv);
                }
            }
        }
    }

    // ---------------- output stage: out = v0 @ W_out + b_out ----------------
    __syncthreads();
    for (int i = t; i < 2560; i += 1024) aux[i] = Wo[i];
    __syncthreads();
    {
        const int m = t >> 3;        // 0..127
        const int o = t & 7;
        float s = bo[o];
        for (int kb = 0; kb < 256; kb += 8) {
            const int off = (kb >> 5) * 4096 + (m >> 4) * 512 +
                            (((kb >> 3) & 3) * 16 + (m & 15)) * 8;
            ushort4 h0 = *(const ushort4*)&state[off];
            ushort4 h1 = *(const ushort4*)&state[off + 4];
            s += h2f(h0.x) * aux[(kb + 0) * 10 + o] + h2f(h0.y) * aux[(kb + 1) * 10 + o]
               + h2f(h0.z) * aux[(kb + 2) * 10 + o] + h2f(h0.w) * aux[(kb + 3) * 10 + o]
               + h2f(h1.x) * aux[(kb + 4) * 10 + o] + h2f(h1.y) * aux[(kb + 5) * 10 + o]
               + h2f(h1.z) * aux[(kb + 6) * 10 + o] + h2f(h1.w) * aux[(kb + 7) * 10 + o];
        }
        out[(size_t)(b0 + m) * 10 + o] = s;
    }
    if (t < 256) {
        const int m = t >> 1;
        const int o = 8 + (t & 1);
        float s = bo[o];
        for (int kb = 0; kb < 256; kb += 8) {
            const int off = (kb >> 5) * 4096 + (m >> 4) * 512 +
                            (((kb >> 3) & 3) * 16 + (m & 15)) * 8;
            ushort4 h0 = *(const ushort4*)&state[off];
            ushort4 h1 = *(const ushort4*)&state[off + 4];
            s += h2f(h0.x) * aux[(kb + 0) * 10 + o] + h2f(h0.y) * aux[(kb + 1) * 10 + o]
               + h2f(h0.z) * aux[(kb + 2) * 10 + o] + h2f(h0.w) * aux[(kb + 3) * 10 + o]
               + h2f(h1.x) * aux[(kb + 4) * 10 + o] + h2f(h1.y) * aux[(kb + 5) * 10 + o]
               + h2f(h1.z) * aux[(kb + 6) * 10 + o] + h2f(h1.w) * aux[(kb + 7) * 10 + o];
        }
        out[(size_t)(b0 + m) * 10 + o] = s;
    }
}

// ============================================================================
// R11 prep: K-split GEMMs (256 blocks/dispatch = full chip; per-CU LDS work
// halves), virtual-X0 epilogues (no seed materialization), fused dispatches.
// Split matrices live as two partial buffers D and D+HS; consumers sum.
// ============================================================================

template<bool S>
__device__ __forceinline__ float4 ld4(const float* __restrict__ p, size_t idx) {
    float4 v = *(const float4*)(p + idx);
    if constexpr (S) {
        float4 w = *(const float4*)(p + idx + HS);
        v.x += w.x; v.y += w.y; v.z += w.z; v.w += w.w;
    }
    return v;
}

// One 64x64 tile, K-range [kh*KLEN, kh*KLEN+KLEN). acc = A^T B over that range.
// EPI: 0 D=acc | 1 D=acc+2I & Gershgorin rowsum->scr (KLEN=256 only)
//      2 D=2E-acc | 3 D=ca*E+cb*acc | 4 D=2ca*I+2cb*E-ca*E2-cb*acc
// (EPI 2/3/4 emit the constant/E terms only on the kh==0 half.)
template<int EPI, int KLEN, bool AS, bool BS, bool ES>
__device__ __forceinline__ void gemm_body(float* __restrict__ D,
        const float* __restrict__ A, const float* __restrict__ Bm,
        const float* __restrict__ E, const float* __restrict__ E2,
        const float* __restrict__ scr_r, float* __restrict__ scr_w,
        int i, int u0, int v0, int kh)
{
    __shared__ float As[16][64];
    __shared__ float Bs[16][64];
    const size_t off = (size_t)i * 65536;
    const int t  = threadIdx.x;
    const int tx = t & 15, ty = t >> 4;
    const int lk = t >> 4, lv = (t & 15) << 2;

    float ca = 0.f, cb = 0.f;
    if (EPI == 3 || EPI == 4) {        // NS seed coefficients from rowsums
        float* red = &As[0][0];
        red[t] = scr_r[i * 256 + t];
        __syncthreads();
        for (int o = 128; o >= 1; o >>= 1) {
            if (t < o) red[t] = fmaxf(red[t], red[t + o]);
            __syncthreads();
        }
        const float bt_ = red[0];                  // >= lambda_max; lambda_min >= 2
        const float r = (2.f + bt_) * (2.f + bt_) / (8.f * bt_);
        const float e = (r - 1.f) / (r + 1.f);
        cb = -(1.f - e) / (2.f * bt_);
        ca = -cb * (2.f + bt_);
        __syncthreads();
    }

    const int kb = kh * KLEN;
    float acc[4][4];
#pragma unroll
    for (int m = 0; m < 4; ++m)
#pragma unroll
        for (int n = 0; n < 4; ++n) acc[m][n] = 0.f;

    float4 an = ld4<AS>(A, off + (size_t)(kb + lk) * 256 + u0 + lv);
    float4 bn = ld4<BS>(Bm, off + (size_t)(kb + lk) * 256 + v0 + lv);

    for (int k0 = 0; k0 < KLEN; k0 += 16) {
        if (k0) __syncthreads();
        *(float4*)&As[lk][lv] = an;
        *(float4*)&Bs[lk][lv] = bn;
        if (k0 < KLEN - 16) {
            an = ld4<AS>(A, off + (size_t)(kb + k0 + 16 + lk) * 256 + u0 + lv);
            bn = ld4<BS>(Bm, off + (size_t)(kb + k0 + 16 + lk) * 256 + v0 + lv);
        }
        __syncthreads();
#pragma unroll
        for (int kk = 0; kk < 16; ++kk) {
            float af[4], bf[4];
            *(float4*)&af[0] = *(const float4*)&As[kk][ty * 4];
            *(float4*)&bf[0] = *(const float4*)&Bs[kk][tx * 4];
#pragma unroll
            for (int m = 0; m < 4; ++m)
#pragma unroll
                for (int n = 0; n < 4; ++n) acc[m][n] += af[m] * bf[n];
        }
    }

    float* Dp = D + (size_t)kh * HS;   // split kernels write their half
#pragma unroll
    for (int m = 0; m < 4; ++m) {
        const int u = u0 + ty * 4 + m;
        const size_t idx = off + (size_t)u * 256 + v0 + tx * 4;
        float4 r; float* rf = &r.x;
        if (EPI == 0) {
#pragma unroll
            for (int n = 0; n < 4; ++n) rf[n] = acc[m][n];
        } else if (EPI == 1) {
#pragma unroll
            for (int n = 0; n < 4; ++n)
                rf[n] = acc[m][n] + ((u == v0 + tx * 4 + n) ? 2.f : 0.f);
        } else if (EPI == 2) {
            if (kh == 0) {
                float4 e4 = ld4<ES>(E, idx); const float* ef = &e4.x;
#pragma unroll
                for (int n = 0; n < 4; ++n) rf[n] = 2.f * ef[n] - acc[m][n];
            } else {
#pragma unroll
                for (int n = 0; n < 4; ++n) rf[n] = -acc[m][n];
            }
        } else if (EPI == 3) {
            if (kh == 0) {
                float4 e4 = ld4<ES>(E, idx); const float* ef = &e4.x;
#pragma unroll
                for (int n = 0; n < 4; ++n) rf[n] = ca * ef[n] + cb * acc[m][n];
            } else {
#pragma unroll
                for (int n = 0; n < 4; ++n) rf[n] = cb * acc[m][n];
            }
        } else {   // EPI 4
            if (kh == 0) {
                float4 e4 = ld4<ES>(E, idx); const float* ef = &e4.x;
                float4 f4 = ld4<true>(E2, idx); const float* ff = &f4.x;
#pragma unroll
                for (int n = 0; n < 4; ++n)
                    rf[n] = 2.f * ca * ((u == v0 + tx * 4 + n) ? 1.f : 0.f)
                          + 2.f * cb * ef[n] - ca * ff[n] - cb * acc[m][n];
            } else {
#pragma unroll
                for (int n = 0; n < 4; ++n) rf[n] = -cb * acc[m][n];
            }
        }
        *(float4*)&Dp[idx] = r;
        if (EPI == 1) {                // Gershgorin rowsum (full C, exact)
            float s = fabsf(rf[0]) + fabsf(rf[1]) + fabsf(rf[2]) + fabsf(rf[3]);
            s += __shfl_xor(s, 1); s += __shfl_xor(s, 2);
            s += __shfl_xor(s, 4); s += __shfl_xor(s, 8);
            if (tx == 0) atomicAdd(&scr_w[i * 256 + u], s);
        }
    }
}

// K1: C = B0^T B0 + 2I (unsplit, rowsum) | Bt transpose | Wi transpose-pack
__launch_bounds__(256)
__global__ void k1_fused(const float* __restrict__ B0, const float* __restrict__ W_in,
                         float* __restrict__ C, float* __restrict__ Bt,
                         u16* __restrict__ Wi, float* __restrict__ scr)
{
    const int b = blockIdx.x;
    const int t = threadIdx.x;
    if (b < 128) {
        const int i = b >> 4, tile = b & 15;
        gemm_body<1, 256, false, false, false>(C, B0, B0, nullptr, nullptr,
                                               nullptr, scr, i,
                                               (tile >> 2) * 64, (tile & 3) * 64, 0);
        return;
    }
    __shared__ float tl[32][33];
    const int tx = t & 31, ty = t >> 5;   // 32 x 8
    if (b < 192) {                        // Bt transpose: 64 blocks
        const int bb = b - 128;
        const int i = bb >> 3;
        const size_t off = (size_t)i * 65536;
        const int u0 = (bb & 7) * 32;
        for (int k0 = 0; k0 < 256; k0 += 32) {
            __syncthreads();
#pragma unroll
            for (int r = 0; r < 32; r += 8)
                tl[ty + r][tx] = B0[off + (size_t)(u0 + ty + r) * 256 + k0 + tx];
            __syncthreads();
#pragma unroll
            for (int r = 0; r < 32; r += 8)
                Bt[off + (size_t)(k0 + ty + r) * 256 + u0 + tx] = tl[tx][ty + r];
        }
    } else {                              // Wi pack: 200 blocks
        const int bb = b - 192;           // 25 k-tiles x 8 u-tiles
        const int k0 = (bb % 25) * 32, u0 = (bb / 25) * 32;
#pragma unroll
        for (int r = 0; r < 32; r += 8) {
            const int k = k0 + ty + r;
            tl[ty + r][tx] = (k < 784) ? W_in[(size_t)k * 256 + u0 + tx] : 0.f;
        }
        __syncthreads();
#pragma unroll
        for (int r = 0; r < 32; r += 8)
            Wi[(size_t)(u0 + ty + r) * 800 + k0 + tx] = f2h(tl[tx][ty + r]);
    }
}

// split GEMM dispatch: grid (4,4,16), z = matrix(0..7) + 8*khalf
template<int EPI, bool AS, bool BS, bool ES>
__launch_bounds__(256)
__global__ void gemmS(float* __restrict__ D, const float* __restrict__ A,
                      const float* __restrict__ Bm, const float* __restrict__ E,
                      const float* __restrict__ E2, const float* __restrict__ scr)
{
    const int z = blockIdx.z;
    gemm_body<EPI, 128, AS, BS, ES>(D, A, Bm, E, E2, scr, nullptr,
                                    z & 7, blockIdx.y * 64, blockIdx.x * 64, z >> 3);
}

// K9: R = B*P (z 0..15) | Q = B*M (z 16..31) | cc (z==32, 8 blocks)
__launch_bounds__(256)
__global__ void gemmRQcc(float* __restrict__ R, float* __restrict__ Q,
                         const float* __restrict__ Bt, const float* __restrict__ P,
                         const float* __restrict__ M, const float* __restrict__ B0,
                         const float* __restrict__ q, float* __restrict__ cc)
{
    const int z = blockIdx.z;
    if (z < 16) {
        gemm_body<0, 128, false, true, false>(R, Bt, P, nullptr, nullptr, nullptr,
                nullptr, z & 7, blockIdx.y * 64, blockIdx.x * 64, z >> 3);
        return;
    }
    if (z < 32) {
        const int zz = z - 16;
        gemm_body<0, 128, false, true, false>(Q, Bt, M, nullptr, nullptr, nullptr,
                nullptr, zz & 7, blockIdx.y * 64, blockIdx.x * 64, zz >> 3);
        return;
    }
    if (blockIdx.y != 0 || blockIdx.x >= 8) return;
    __shared__ float qs[256];
    __shared__ float vs[256];
    __shared__ float c1s[256];
    const int i = blockIdx.x;
    const int u = threadIdx.x;
    const size_t ob = (size_t)i * 65536;
    qs[u] = q[i * 256 + u];
    __syncthreads();
    float s0 = 0.f;
    for (int k = 0; k < 256; ++k) s0 += B0[ob + (size_t)k * 256 + u] * qs[k];
    vs[u] = 0.1f * s0;
    __syncthreads();
    float s = 0.f;
    for (int k = 0; k < 256; ++k)
        s += (M[ob + (size_t)k * 256 + u] + M[ob + HS + (size_t)k * 256 + u]) * vs[k];
    c1s[u] = s;
    cc[i * 512 + 256 + u] = s;
    __syncthreads();
    float s2 = 0.f;
    for (int k = 0; k < 256; ++k) s2 += Bt[ob + (size_t)k * 256 + u] * c1s[k];
    cc[i * 512 + u] = 0.1f * qs[u] - s2;
}

// Wc[i][c][512] f16 pack; P,R,Q,M split; all reads row-contiguous
__launch_bounds__(256)
__global__ void pack_wcomb(const float* __restrict__ P, const float* __restrict__ R,
                           const float* __restrict__ Q, const float* __restrict__ M,
                           u16* __restrict__ W)
{
    const int i = blockIdx.y;
    const int e = blockIdx.x * 256 + threadIdx.x;   // 0..262143
    const int c = e >> 9, k = e & 511;
    const size_t off = (size_t)i * 65536;
    float v;
    if (c < 256) {        // z0 row u=c: [I - R | -P^T]
        if (k < 256) {
            const size_t idx = off + (size_t)c * 256 + k;
            v = ((c == k) ? 1.f : 0.f) - (R[idx] + R[idx + HS]);
        } else {
            const size_t idx = off + (size_t)c * 256 + (k - 256);
            v = -(Q[idx] + Q[idx + HS]);
        }
    } else {              // z1 row u=c-256: [P | M]
        const int u = c - 256;
        if (k < 256) {
            const size_t idx = off + (size_t)u * 256 + k;
            v = P[idx] + P[idx + HS];
        } else {
            const size_t idx = off + (size_t)u * 256 + (k - 256);
            v = M[idx] + M[idx + HS];
        }
    }
    W[(size_t)i * 262144 + (size_t)c * 512 + k] = f2h(v);
}

extern "C" void kernel_launch(void* const* d_in, const int* in_sizes, int n_in,
                              void* d_out, int out_size, void* d_ws, size_t ws_size,
                              hipStream_t stream)
{
    const float* x     = (const float*)d_in[0];
    const float* W_in  = (const float*)d_in[1];
    const float* b_in  = (const float*)d_in[2];
    const float* B0    = (const float*)d_in[3];
    const float* q     = (const float*)d_in[4];
    const float* W_out = (const float*)d_in[5];
    const float* b_out = (const float*)d_in[6];

    u16* Wc = (u16*)d_ws;                  // 8 * 262144 u16 = 4 MB
    u16* Wi = Wc + 8 * 262144;             // 256*800 u16
    float* cc = (float*)(Wi + 204800);     // 8*512 floats
    float* F  = cc + 4096;
    float* Bt   = F;                       // 1 slot (plain)
    float* Cm   = F + 1 * HS;              // 1 slot (plain)
    float* bufA = F + 2 * HS;              // 2 slots (split): Y1 / Y2 / Y3 / R
    float* bufB = F + 4 * HS;              // 2 slots: X1 / M
    float* bufC = F + 6 * HS;              // 2 slots: X2 / P
    float* bufD = F + 8 * HS;              // 2 slots: Q
    float* scr  = F + 10 * HS;             // 2048 floats (rowsums)

    hipMemsetAsync(scr, 0, 2048 * sizeof(float), stream);

    // K1: C = B0^T B0 + 2I (+rowsum) | Bt | Wi
    k1_fused<<<392, 256, 0, stream>>>(B0, W_in, Cm, Bt, Wi, scr);
    // NS iteration 1 with virtual X0 = aI + bC:
    gemmS<3, false, false, false><<<dim3(4, 4, 16), 256, 0, stream>>>(
        bufA, Cm, Cm, Cm, nullptr, scr);                    // Y1 = aC + bC^2
    gemmS<4, false, true, false><<<dim3(4, 4, 16), 256, 0, stream>>>(
        bufB, Cm, bufA, Cm, bufA, scr);                     // X1 = 2X0 - X0*Y1
    // NS iteration 2:
    gemmS<0, false, true, false><<<dim3(4, 4, 16), 256, 0, stream>>>(
        bufA, Cm, bufB, nullptr, nullptr, nullptr);         // Y2 = C*X1
    gemmS<2, true, true, true><<<dim3(4, 4, 16), 256, 0, stream>>>(
        bufC, bufB, bufA, bufB, nullptr, nullptr);          // X2 = 2X1 - X1*Y2
    // NS iteration 3:
    gemmS<0, false, true, false><<<dim3(4, 4, 16), 256, 0, stream>>>(
        bufA, Cm, bufC, nullptr, nullptr, nullptr);         // Y3 = C*X2
    gemmS<2, true, true, true><<<dim3(4, 4, 16), 256, 0, stream>>>(
        bufB, bufC, bufA, bufC, nullptr, nullptr);          // M = 2X2 - X2*Y3
    // P = M B^T:
    gemmS<0, true, false, false><<<dim3(4, 4, 16), 256, 0, stream>>>(
        bufC, bufB, Bt, nullptr, nullptr, nullptr);         // P
    // R = B P | Q = B M | cc:
    gemmRQcc<<<dim3(4, 4, 33), 256, 0, stream>>>(bufA, bufD, Bt, bufC, bufB, B0, q, cc);
    // pack (P=bufC, R=bufA, Q=bufD, M=bufB):
    pack_wcomb<<<dim3(1024, 8), 256, 0, stream>>>(bufC, bufA, bufD, bufB, Wc);

    // ---- the whole network in one kernel ----
    meganet<<<BATCH_N / 128, 1024, 0, stream>>>(
        x, Wi, b_in, Wc, cc, W_out, b_out, (float*)d_out);
}